// Round 13
// baseline (590.447 us; speedup 1.0000x reference)
//
#include <hip/hip_runtime.h>

#define N_NODES 100000
#define IN_C 32
#define HID_C 64
#define OUT_C 5
#define N_EDGES 1600000
#define SCAN_BLK 1024
#define N_SCAN_BLKS ((N_NODES + SCAN_BLK - 1) / SCAN_BLK)   // 98
#define N_TILES ((N_NODES + 63) / 64)                        // 1563

// dst-space partitioning for XCD-local scatter writes.
#define N_PART 8
#define PART_NODES 12500
#define CHUNK_E 4096
#define NCHUNK ((N_EDGES + CHUNK_E - 1) / CHUNK_E)           // 391
#define BUILD_BLOCKS 2048

__device__ __forceinline__ unsigned short f2bf(float f) {
  unsigned int u = __float_as_uint(f);
  unsigned int r = (u + 0x7FFFu + ((u >> 16) & 1u)) >> 16;  // RNE
  return (unsigned short)r;
}
__device__ __forceinline__ float bf2f(unsigned short b) {
  return __uint_as_float(((unsigned int)b) << 16);
}
__device__ __forceinline__ int get_xcc() {
  unsigned int x;
  asm volatile("s_getreg_b32 %0, hwreg(HW_REG_XCC_ID)" : "=s"(x));
  return (int)(x & 7u);
}

// ---------------------------------------------------------------------------
// Convert x (f32 [N,32]) -> xb (bf16).
// ---------------------------------------------------------------------------
__global__ __launch_bounds__(256) void convert_x_kernel(
    const float* __restrict__ x, unsigned short* __restrict__ xb) {
  int t = blockIdx.x * blockDim.x + threadIdx.x;
  if (t >= N_NODES * IN_C / 4) return;
  float4 v = ((const float4*)x)[t];
  ushort4 o;
  o.x = f2bf(v.x); o.y = f2bf(v.y); o.z = f2bf(v.z); o.w = f2bf(v.w);
  ((ushort4*)xb)[t] = o;
}

// ---------------------------------------------------------------------------
// CSR build step 1: histogram of dst. XCD-aware work-stealing: block drains
// the queue of its own XCD's partition first, then steals (correct for ANY
// value of XCC_ID — all queues always drained). int4 loads -> 4 independent
// atomic chains per iteration.
// ---------------------------------------------------------------------------
__global__ __launch_bounds__(256) void deg_count_kernel(
    const int* __restrict__ dst, int* __restrict__ cnt, int* __restrict__ work) {
  __shared__ int sc;
  int xcc = get_xcc();
  for (int rr = 0; rr < N_PART; ++rr) {
    int r = (xcc + rr) & (N_PART - 1);
    int lo = r * PART_NODES;
    while (true) {
      if (threadIdx.x == 0) sc = atomicAdd(&work[r], 1);
      __syncthreads();
      int c = sc;
      __syncthreads();
      if (c >= NCHUNK) break;
      int base = c * CHUNK_E;
#pragma unroll
      for (int it = 0; it < CHUNK_E / 4 / 256; ++it) {
        int e = base + ((it << 8) + threadIdx.x) * 4;
        if (e < N_EDGES) {  // N_EDGES%4==0, e%4==0 -> e+3 in range
          int4 d4 = *(const int4*)(dst + e);
          if ((unsigned)(d4.x - lo) < PART_NODES) atomicAdd(&cnt[d4.x], 1);
          if ((unsigned)(d4.y - lo) < PART_NODES) atomicAdd(&cnt[d4.y], 1);
          if ((unsigned)(d4.z - lo) < PART_NODES) atomicAdd(&cnt[d4.z], 1);
          if ((unsigned)(d4.w - lo) < PART_NODES) atomicAdd(&cnt[d4.w], 1);
        }
      }
    }
  }
}

// ---------------------------------------------------------------------------
// CSR build step 2a: per-block inclusive scan of cnt.
// ---------------------------------------------------------------------------
__global__ __launch_bounds__(SCAN_BLK) void scan1_kernel(
    const int* __restrict__ cnt, int* __restrict__ rowptr,
    int* __restrict__ partial) {
  __shared__ int s[SCAN_BLK];
  int t = threadIdx.x;
  int g = blockIdx.x * SCAN_BLK + t;
  int v = (g < N_NODES) ? cnt[g] : 0;
  s[t] = v;
  __syncthreads();
#pragma unroll
  for (int off = 1; off < SCAN_BLK; off <<= 1) {
    int u = (t >= off) ? s[t - off] : 0;
    __syncthreads();
    s[t] += u;
    __syncthreads();
  }
  if (g < N_NODES) rowptr[g + 1] = s[t];
  if (t == SCAN_BLK - 1) partial[blockIdx.x] = s[t];
}

// ---------------------------------------------------------------------------
// CSR build step 2b: exclusive scan of block totals (single block).
// ---------------------------------------------------------------------------
__global__ __launch_bounds__(128) void scan2_kernel(int* __restrict__ partial) {
  __shared__ int s[128];
  int t = threadIdx.x;
  int v = (t < N_SCAN_BLKS) ? partial[t] : 0;
  s[t] = v;
  __syncthreads();
#pragma unroll
  for (int off = 1; off < 128; off <<= 1) {
    int u = (t >= off) ? s[t - off] : 0;
    __syncthreads();
    s[t] += u;
    __syncthreads();
  }
  if (t < N_SCAN_BLKS) partial[t] = s[t] - v;  // exclusive
}

// ---------------------------------------------------------------------------
// CSR build step 2c: add block offsets; seed cursor[] = rowptr[].
// ---------------------------------------------------------------------------
__global__ __launch_bounds__(256) void scan3_kernel(
    int* __restrict__ rowptr, const int* __restrict__ partial,
    int* __restrict__ cursor) {
  int i = blockIdx.x * blockDim.x + threadIdx.x;
  if (i >= N_NODES) return;
  int val = rowptr[i + 1] + partial[i >> 10];
  rowptr[i + 1] = val;
  if (i + 1 < N_NODES) cursor[i + 1] = val;
  if (i == 0) { rowptr[0] = 0; cursor[0] = 0; }
}

// ---------------------------------------------------------------------------
// CSR build step 3: fill csr_src. Same XCD-aware work-stealing + int4 MLP.
// ---------------------------------------------------------------------------
__global__ __launch_bounds__(256) void fill_kernel(
    const int* __restrict__ src, const int* __restrict__ dst,
    int* __restrict__ cursor, int* __restrict__ csr_src,
    int* __restrict__ work) {
  __shared__ int sc;
  int xcc = get_xcc();
  for (int rr = 0; rr < N_PART; ++rr) {
    int r = (xcc + rr) & (N_PART - 1);
    int lo = r * PART_NODES;
    while (true) {
      if (threadIdx.x == 0) sc = atomicAdd(&work[r], 1);
      __syncthreads();
      int c = sc;
      __syncthreads();
      if (c >= NCHUNK) break;
      int base = c * CHUNK_E;
#pragma unroll
      for (int it = 0; it < CHUNK_E / 4 / 256; ++it) {
        int e = base + ((it << 8) + threadIdx.x) * 4;
        if (e < N_EDGES) {
          int4 d4 = *(const int4*)(dst + e);
          bool hx = (unsigned)(d4.x - lo) < PART_NODES;
          bool hy = (unsigned)(d4.y - lo) < PART_NODES;
          bool hz = (unsigned)(d4.z - lo) < PART_NODES;
          bool hw = (unsigned)(d4.w - lo) < PART_NODES;
          if (hx | hy | hz | hw) {
            int4 s4 = *(const int4*)(src + e);
            if (hx) { int p = atomicAdd(&cursor[d4.x], 1); csr_src[p] = s4.x; }
            if (hy) { int p = atomicAdd(&cursor[d4.y], 1); csr_src[p] = s4.y; }
            if (hz) { int p = atomicAdd(&cursor[d4.z], 1); csr_src[p] = s4.z; }
            if (hw) { int p = atomicAdd(&cursor[d4.w], 1); csr_src[p] = s4.w; }
          }
        }
      }
    }
  }
}

// ---------------------------------------------------------------------------
// Mean aggregation layer 1 (gather of bf16 x rows, f32 accumulate).
// ---------------------------------------------------------------------------
__global__ __launch_bounds__(256) void agg_mean1_kernel(
    const unsigned short* __restrict__ xb, const int* __restrict__ rowptr,
    const int* __restrict__ csr, float* __restrict__ mean) {
  int t = blockIdx.x * blockDim.x + threadIdx.x;
  if (t >= N_NODES * (IN_C / 4)) return;
  int node = t >> 3;
  int q = t & 7;
  int p0 = rowptr[node], p1 = rowptr[node + 1];
  const ushort4* xb4 = (const ushort4*)xb;
  float ax = 0.f, ay = 0.f, az = 0.f, aw = 0.f;
  int k = p0;
  for (; k + 4 <= p1; k += 4) {
    int s0 = csr[k], s1 = csr[k + 1], s2 = csr[k + 2], s3 = csr[k + 3];
    ushort4 a = xb4[s0 * 8 + q];
    ushort4 b = xb4[s1 * 8 + q];
    ushort4 c = xb4[s2 * 8 + q];
    ushort4 d = xb4[s3 * 8 + q];
    ax += bf2f(a.x) + bf2f(b.x) + bf2f(c.x) + bf2f(d.x);
    ay += bf2f(a.y) + bf2f(b.y) + bf2f(c.y) + bf2f(d.y);
    az += bf2f(a.z) + bf2f(b.z) + bf2f(c.z) + bf2f(d.z);
    aw += bf2f(a.w) + bf2f(b.w) + bf2f(c.w) + bf2f(d.w);
  }
  for (; k < p1; ++k) {
    ushort4 a = xb4[csr[k] * 8 + q];
    ax += bf2f(a.x); ay += bf2f(a.y); az += bf2f(a.z); aw += bf2f(a.w);
  }
  float inv = 1.0f / fmaxf((float)(p1 - p0), 1.0f);
  float4 o; o.x = ax * inv; o.y = ay * inv; o.z = az * inv; o.w = aw * inv;
  ((float4*)mean)[t] = o;
}

// ---------------------------------------------------------------------------
// Mean aggregation layer 2 (gather of bf16 h1 rows, f32 accumulate).
// ---------------------------------------------------------------------------
__global__ __launch_bounds__(256) void agg_mean2_kernel(
    const unsigned short* __restrict__ hb, const int* __restrict__ rowptr,
    const int* __restrict__ csr, float* __restrict__ mean) {
  int t = blockIdx.x * blockDim.x + threadIdx.x;
  if (t >= N_NODES * (HID_C / 4)) return;
  int node = t >> 4;
  int q = t & 15;
  int p0 = rowptr[node], p1 = rowptr[node + 1];
  const ushort4* hb4 = (const ushort4*)hb;
  float ax = 0.f, ay = 0.f, az = 0.f, aw = 0.f;
  int k = p0;
  for (; k + 4 <= p1; k += 4) {
    int s0 = csr[k], s1 = csr[k + 1], s2 = csr[k + 2], s3 = csr[k + 3];
    ushort4 a = hb4[s0 * 16 + q];
    ushort4 b = hb4[s1 * 16 + q];
    ushort4 c = hb4[s2 * 16 + q];
    ushort4 d = hb4[s3 * 16 + q];
    ax += bf2f(a.x) + bf2f(b.x) + bf2f(c.x) + bf2f(d.x);
    ay += bf2f(a.y) + bf2f(b.y) + bf2f(c.y) + bf2f(d.y);
    az += bf2f(a.z) + bf2f(b.z) + bf2f(c.z) + bf2f(d.z);
    aw += bf2f(a.w) + bf2f(b.w) + bf2f(c.w) + bf2f(d.w);
  }
  for (; k < p1; ++k) {
    ushort4 a = hb4[csr[k] * 16 + q];
    ax += bf2f(a.x); ay += bf2f(a.y); az += bf2f(a.z); aw += bf2f(a.w);
  }
  float inv = 1.0f / fmaxf((float)(p1 - p0), 1.0f);
  float4 o; o.x = ax * inv; o.y = ay * inv; o.z = az * inv; o.w = aw * inv;
  ((float4*)mean)[t] = o;
}

// ---------------------------------------------------------------------------
// Layer 1 tiled GEMM; epilogue writes h1 (f32) AND h1b (bf16).
// ---------------------------------------------------------------------------
__global__ __launch_bounds__(256) void layer1_gemm_kernel(
    const float* __restrict__ x, const float* __restrict__ mean,
    const float* __restrict__ Wl, const float* __restrict__ bl,
    const float* __restrict__ Wr, float* __restrict__ h1,
    unsigned short* __restrict__ h1b) {
  const int LD = 17;  // float4 row stride (16 data + 1 pad)
  __shared__ float4 sA[64 * LD];
  __shared__ float4 sB[64 * LD];
  __shared__ float sbias[64];
  int tid = threadIdx.x;
  int base = blockIdx.x * 64;
  const float4* mean4 = (const float4*)mean;
  const float4* x4 = (const float4*)x;
  const float4* Wl4 = (const float4*)Wl;
  const float4* Wr4 = (const float4*)Wr;
  const float4 zero = make_float4(0.f, 0.f, 0.f, 0.f);
  for (int idx = tid; idx < 64 * 16; idx += 256) {
    int row = idx >> 4, col = idx & 15;
    int node = base + row;
    float4 v = zero;
    if (node < N_NODES)
      v = (col < 8) ? mean4[node * 8 + col] : x4[node * 8 + (col - 8)];
    sA[row * LD + col] = v;
    sB[row * LD + col] = (col < 8) ? Wl4[row * 8 + col] : Wr4[row * 8 + (col - 8)];
  }
  if (tid < 64) sbias[tid] = bl[tid];
  __syncthreads();

  int tn = tid & 15;
  int to = tid >> 4;
  float acc[4][4];
#pragma unroll
  for (int i = 0; i < 4; ++i)
#pragma unroll
    for (int j = 0; j < 4; ++j) acc[i][j] = 0.f;

#pragma unroll 4
  for (int k4 = 0; k4 < 16; ++k4) {
    float4 a[4], b[4];
#pragma unroll
    for (int i = 0; i < 4; ++i) a[i] = sA[(tn + i * 16) * LD + k4];
#pragma unroll
    for (int j = 0; j < 4; ++j) b[j] = sB[(to * 4 + j) * LD + k4];
#pragma unroll
    for (int i = 0; i < 4; ++i)
#pragma unroll
      for (int j = 0; j < 4; ++j) {
        acc[i][j] = fmaf(a[i].x, b[j].x, acc[i][j]);
        acc[i][j] = fmaf(a[i].y, b[j].y, acc[i][j]);
        acc[i][j] = fmaf(a[i].z, b[j].z, acc[i][j]);
        acc[i][j] = fmaf(a[i].w, b[j].w, acc[i][j]);
      }
  }

  float4* h14 = (float4*)h1;
  ushort4* h1b4 = (ushort4*)h1b;
#pragma unroll
  for (int i = 0; i < 4; ++i) {
    int node = base + tn + i * 16;
    if (node < N_NODES) {
      float4 v;
      v.x = fmaxf(acc[i][0] + sbias[to * 4 + 0], 0.f);
      v.y = fmaxf(acc[i][1] + sbias[to * 4 + 1], 0.f);
      v.z = fmaxf(acc[i][2] + sbias[to * 4 + 2], 0.f);
      v.w = fmaxf(acc[i][3] + sbias[to * 4 + 3], 0.f);
      h14[node * 16 + to] = v;
      ushort4 hb;
      hb.x = f2bf(v.x); hb.y = f2bf(v.y); hb.z = f2bf(v.z); hb.w = f2bf(v.w);
      h1b4[node * 16 + to] = hb;
    }
  }
}

// ---------------------------------------------------------------------------
// Layer 2 + head fused.
// ---------------------------------------------------------------------------
__global__ __launch_bounds__(256) void layer2_head_kernel(
    const float* __restrict__ h1, const float* __restrict__ mean,
    const float* __restrict__ Wl, const float* __restrict__ bl,
    const float* __restrict__ Wr,
    const float* __restrict__ Wlin, const float* __restrict__ blin,
    float* __restrict__ out) {
  const int LD = 33;  // float4 row stride (32 data + 1 pad)
  __shared__ float4 sA[64 * LD];
  __shared__ float4 sB[64 * LD];
  __shared__ float sbias[64];
  __shared__ float sWlin[OUT_C * 64];
  __shared__ float sblin[OUT_C];
  int tid = threadIdx.x;
  int base = blockIdx.x * 64;
  const float4* mean4 = (const float4*)mean;
  const float4* h14 = (const float4*)h1;
  const float4* Wl4 = (const float4*)Wl;
  const float4* Wr4 = (const float4*)Wr;
  const float4 zero = make_float4(0.f, 0.f, 0.f, 0.f);
  for (int idx = tid; idx < 64 * 32; idx += 256) {
    int row = idx >> 5, col = idx & 31;
    int node = base + row;
    float4 v = zero;
    if (node < N_NODES)
      v = (col < 16) ? mean4[node * 16 + col] : h14[node * 16 + (col - 16)];
    sA[row * LD + col] = v;
    sB[row * LD + col] = (col < 16) ? Wl4[row * 16 + col] : Wr4[row * 16 + (col - 16)];
  }
  if (tid < 64) sbias[tid] = bl[tid];
  for (int i = tid; i < OUT_C * 64; i += 256) sWlin[i] = Wlin[i];
  if (tid < OUT_C) sblin[tid] = blin[tid];
  __syncthreads();

  int tn = tid & 15;
  int to = tid >> 4;
  float acc[4][4];
#pragma unroll
  for (int i = 0; i < 4; ++i)
#pragma unroll
    for (int j = 0; j < 4; ++j) acc[i][j] = 0.f;

#pragma unroll 4
  for (int k4 = 0; k4 < 32; ++k4) {
    float4 a[4], b[4];
#pragma unroll
    for (int i = 0; i < 4; ++i) a[i] = sA[(tn + i * 16) * LD + k4];
#pragma unroll
    for (int j = 0; j < 4; ++j) b[j] = sB[(to * 4 + j) * LD + k4];
#pragma unroll
    for (int i = 0; i < 4; ++i)
#pragma unroll
      for (int j = 0; j < 4; ++j) {
        acc[i][j] = fmaf(a[i].x, b[j].x, acc[i][j]);
        acc[i][j] = fmaf(a[i].y, b[j].y, acc[i][j]);
        acc[i][j] = fmaf(a[i].z, b[j].z, acc[i][j]);
        acc[i][j] = fmaf(a[i].w, b[j].w, acc[i][j]);
      }
  }

  __syncthreads();
  float* sH = (float*)sA;
  const int LDH = 69;
#pragma unroll
  for (int i = 0; i < 4; ++i) {
    int r = tn + i * 16;
#pragma unroll
    for (int j = 0; j < 4; ++j) {
      sH[r * LDH + to * 4 + j] = fmaxf(acc[i][j] + sbias[to * 4 + j], 0.f);
    }
  }
  __syncthreads();

  if (tid < 64) {
    int node = base + tid;
    if (node < N_NODES) {
      float o5[OUT_C];
#pragma unroll
      for (int m = 0; m < OUT_C; ++m) o5[m] = sblin[m];
      const float* hr = &sH[tid * LDH];
#pragma unroll 8
      for (int c = 0; c < HID_C; ++c) {
        float v = hr[c];
#pragma unroll
        for (int m = 0; m < OUT_C; ++m) o5[m] = fmaf(v, sWlin[m * 64 + c], o5[m]);
      }
#pragma unroll
      for (int m = 0; m < OUT_C; ++m) out[node * OUT_C + m] = o5[m];
    }
  }
}

extern "C" void kernel_launch(void* const* d_in, const int* in_sizes, int n_in,
                              void* d_out, int out_size, void* d_ws, size_t ws_size,
                              hipStream_t stream) {
  const float* x    = (const float*)d_in[0];
  const int*   ei   = (const int*)d_in[1];
  const float* W1l  = (const float*)d_in[2];
  const float* b1   = (const float*)d_in[3];
  const float* W1r  = (const float*)d_in[4];
  const float* W2l  = (const float*)d_in[5];
  const float* b2   = (const float*)d_in[6];
  const float* W2r  = (const float*)d_in[7];
  const float* Wlin = (const float*)d_in[8];
  const float* blin = (const float*)d_in[9];

  const int* src = ei;
  const int* dst = ei + N_EDGES;

  // Workspace layout (4B units):
  //   rowptr  [100004]
  //   cursor  [100000]   (doubles as histogram)
  //   work    [16]       (deg queue 0:8, fill queue 8:16)
  //   partial [128]
  //   csr_src [1600000]
  //   xb      [N*32/2]   (bf16 x)
  //   h1b     [N*64/2]   (bf16 h1)
  //   mean    [N*64]
  //   h1      [N*64]
  int* rowptr  = (int*)d_ws;
  int* cursor  = rowptr + 100004;
  int* work    = cursor + N_NODES;
  int* partial = work + 16;
  int* csr_src = partial + 128;
  unsigned short* xb  = (unsigned short*)(csr_src + N_EDGES);
  unsigned short* h1b = xb + (size_t)N_NODES * IN_C;
  float* mean  = (float*)(h1b + (size_t)N_NODES * HID_C);
  float* h1    = mean + (size_t)N_NODES * HID_C;

  // zero cursor (histogram) + work queues in one memset
  hipMemsetAsync(cursor, 0, (size_t)(N_NODES + 16) * sizeof(int), stream);

  convert_x_kernel<<<(N_NODES * IN_C / 4 + 255) / 256, 256, 0, stream>>>(x, xb);
  deg_count_kernel<<<BUILD_BLOCKS, 256, 0, stream>>>(dst, cursor, work);
  scan1_kernel<<<N_SCAN_BLKS, SCAN_BLK, 0, stream>>>(cursor, rowptr, partial);
  scan2_kernel<<<1, 128, 0, stream>>>(partial);
  scan3_kernel<<<(N_NODES + 255) / 256, 256, 0, stream>>>(rowptr, partial, cursor);
  fill_kernel<<<BUILD_BLOCKS, 256, 0, stream>>>(src, dst, cursor, csr_src, work + 8);

  agg_mean1_kernel<<<(N_NODES * (IN_C / 4) + 255) / 256, 256, 0, stream>>>(
      xb, rowptr, csr_src, mean);
  layer1_gemm_kernel<<<N_TILES, 256, 0, stream>>>(
      x, mean, W1l, b1, W1r, h1, h1b);
  agg_mean2_kernel<<<(N_NODES * (HID_C / 4) + 255) / 256, 256, 0, stream>>>(
      h1b, rowptr, csr_src, mean);
  layer2_head_kernel<<<N_TILES, 256, 0, stream>>>(
      h1, mean, W2l, b2, W2r, Wlin, blin, (float*)d_out);
}

// Round 14
// 263.142 us; speedup vs baseline: 2.2438x; 2.2438x over previous
//
#include <hip/hip_runtime.h>

#define N_NODES 100000
#define IN_C 32
#define HID_C 64
#define OUT_C 5
#define N_EDGES 1600000
#define SCAN_BLK 1024
#define N_SCAN_BLKS ((N_NODES + SCAN_BLK - 1) / SCAN_BLK)   // 98
#define N_TILES ((N_NODES + 63) / 64)                        // 1563

// dst-space partitioning for XCD-local scatter writes (R9->R12 proven).
#define N_PART 8
#define PART_NODES 12500
#define PART_BLOCKS 2048

__device__ __forceinline__ unsigned short f2bf(float f) {
  unsigned int u = __float_as_uint(f);
  unsigned int r = (u + 0x7FFFu + ((u >> 16) & 1u)) >> 16;  // RNE
  return (unsigned short)r;
}
__device__ __forceinline__ float bf2f(unsigned short b) {
  return __uint_as_float(((unsigned int)b) << 16);
}

// ---------------------------------------------------------------------------
// Convert x (f32 [N,32]) -> xb (bf16).
// ---------------------------------------------------------------------------
__global__ __launch_bounds__(256) void convert_x_kernel(
    const float* __restrict__ x, unsigned short* __restrict__ xb) {
  int t = blockIdx.x * blockDim.x + threadIdx.x;
  if (t >= N_NODES * IN_C / 4) return;
  float4 v = ((const float4*)x)[t];
  ushort4 o;
  o.x = f2bf(v.x); o.y = f2bf(v.y); o.z = f2bf(v.z); o.w = f2bf(v.w);
  ((ushort4*)xb)[t] = o;
}

// ---------------------------------------------------------------------------
// CSR build step 1: histogram of dst (XCD-partitioned, R12-proven) and
// record each edge's rank within its dst row: rank[e] = old count.
// The atomic order is arbitrary but ranks are unique -> valid placement.
// ---------------------------------------------------------------------------
__global__ __launch_bounds__(256) void deg_count_kernel(
    const int* __restrict__ dst, int* __restrict__ cnt,
    int* __restrict__ rank) {
  int r = blockIdx.x & (N_PART - 1);
  int tid = (blockIdx.x >> 3) * 256 + threadIdx.x;
  const int stride = (PART_BLOCKS >> 3) * 256;
  int lo = r * PART_NODES, hi = lo + PART_NODES;
  for (int e = tid; e < N_EDGES; e += stride) {
    int d = dst[e];
    if (d >= lo && d < hi) {
      int rk = atomicAdd(&cnt[d], 1);
      rank[e] = rk;
    }
  }
}

// ---------------------------------------------------------------------------
// CSR build step 2a: per-block inclusive scan of cnt.
// ---------------------------------------------------------------------------
__global__ __launch_bounds__(SCAN_BLK) void scan1_kernel(
    const int* __restrict__ cnt, int* __restrict__ rowptr,
    int* __restrict__ partial) {
  __shared__ int s[SCAN_BLK];
  int t = threadIdx.x;
  int g = blockIdx.x * SCAN_BLK + t;
  int v = (g < N_NODES) ? cnt[g] : 0;
  s[t] = v;
  __syncthreads();
#pragma unroll
  for (int off = 1; off < SCAN_BLK; off <<= 1) {
    int u = (t >= off) ? s[t - off] : 0;
    __syncthreads();
    s[t] += u;
    __syncthreads();
  }
  if (g < N_NODES) rowptr[g + 1] = s[t];
  if (t == SCAN_BLK - 1) partial[blockIdx.x] = s[t];
}

// ---------------------------------------------------------------------------
// CSR build step 2b: exclusive scan of block totals (single block).
// ---------------------------------------------------------------------------
__global__ __launch_bounds__(128) void scan2_kernel(int* __restrict__ partial) {
  __shared__ int s[128];
  int t = threadIdx.x;
  int v = (t < N_SCAN_BLKS) ? partial[t] : 0;
  s[t] = v;
  __syncthreads();
#pragma unroll
  for (int off = 1; off < 128; off <<= 1) {
    int u = (t >= off) ? s[t - off] : 0;
    __syncthreads();
    s[t] += u;
    __syncthreads();
  }
  if (t < N_SCAN_BLKS) partial[t] = s[t] - v;  // exclusive
}

// ---------------------------------------------------------------------------
// CSR build step 2c: add block offsets -> final rowptr.
// ---------------------------------------------------------------------------
__global__ __launch_bounds__(256) void scan3_kernel(
    int* __restrict__ rowptr, const int* __restrict__ partial) {
  int i = blockIdx.x * blockDim.x + threadIdx.x;
  if (i >= N_NODES) return;
  rowptr[i + 1] += partial[i >> 10];
  if (i == 0) rowptr[0] = 0;
}

// ---------------------------------------------------------------------------
// CSR build step 3: fill csr_src — NO atomics. Placement is
// rowptr[dst] + rank[e], precomputed in deg_count. XCD-partitioned writes.
// ---------------------------------------------------------------------------
__global__ __launch_bounds__(256) void fill_kernel(
    const int* __restrict__ src, const int* __restrict__ dst,
    const int* __restrict__ rank, const int* __restrict__ rowptr,
    int* __restrict__ csr_src) {
  int r = blockIdx.x & (N_PART - 1);
  int tid = (blockIdx.x >> 3) * 256 + threadIdx.x;
  const int stride = (PART_BLOCKS >> 3) * 256;
  int lo = r * PART_NODES, hi = lo + PART_NODES;
  for (int e = tid; e < N_EDGES; e += stride) {
    int d = dst[e];
    if (d >= lo && d < hi) {
      csr_src[rowptr[d] + rank[e]] = src[e];
    }
  }
}

// ---------------------------------------------------------------------------
// Mean aggregation layer 1 (gather of bf16 x rows, f32 accumulate).
// ---------------------------------------------------------------------------
__global__ __launch_bounds__(256) void agg_mean1_kernel(
    const unsigned short* __restrict__ xb, const int* __restrict__ rowptr,
    const int* __restrict__ csr, float* __restrict__ mean) {
  int t = blockIdx.x * blockDim.x + threadIdx.x;
  if (t >= N_NODES * (IN_C / 4)) return;
  int node = t >> 3;
  int q = t & 7;
  int p0 = rowptr[node], p1 = rowptr[node + 1];
  const ushort4* xb4 = (const ushort4*)xb;
  float ax = 0.f, ay = 0.f, az = 0.f, aw = 0.f;
  int k = p0;
  for (; k + 4 <= p1; k += 4) {
    int s0 = csr[k], s1 = csr[k + 1], s2 = csr[k + 2], s3 = csr[k + 3];
    ushort4 a = xb4[s0 * 8 + q];
    ushort4 b = xb4[s1 * 8 + q];
    ushort4 c = xb4[s2 * 8 + q];
    ushort4 d = xb4[s3 * 8 + q];
    ax += bf2f(a.x) + bf2f(b.x) + bf2f(c.x) + bf2f(d.x);
    ay += bf2f(a.y) + bf2f(b.y) + bf2f(c.y) + bf2f(d.y);
    az += bf2f(a.z) + bf2f(b.z) + bf2f(c.z) + bf2f(d.z);
    aw += bf2f(a.w) + bf2f(b.w) + bf2f(c.w) + bf2f(d.w);
  }
  for (; k < p1; ++k) {
    ushort4 a = xb4[csr[k] * 8 + q];
    ax += bf2f(a.x); ay += bf2f(a.y); az += bf2f(a.z); aw += bf2f(a.w);
  }
  float inv = 1.0f / fmaxf((float)(p1 - p0), 1.0f);
  float4 o; o.x = ax * inv; o.y = ay * inv; o.z = az * inv; o.w = aw * inv;
  ((float4*)mean)[t] = o;
}

// ---------------------------------------------------------------------------
// Mean aggregation layer 2 (gather of bf16 h1 rows, f32 accumulate).
// ---------------------------------------------------------------------------
__global__ __launch_bounds__(256) void agg_mean2_kernel(
    const unsigned short* __restrict__ hb, const int* __restrict__ rowptr,
    const int* __restrict__ csr, float* __restrict__ mean) {
  int t = blockIdx.x * blockDim.x + threadIdx.x;
  if (t >= N_NODES * (HID_C / 4)) return;
  int node = t >> 4;
  int q = t & 15;
  int p0 = rowptr[node], p1 = rowptr[node + 1];
  const ushort4* hb4 = (const ushort4*)hb;
  float ax = 0.f, ay = 0.f, az = 0.f, aw = 0.f;
  int k = p0;
  for (; k + 4 <= p1; k += 4) {
    int s0 = csr[k], s1 = csr[k + 1], s2 = csr[k + 2], s3 = csr[k + 3];
    ushort4 a = hb4[s0 * 16 + q];
    ushort4 b = hb4[s1 * 16 + q];
    ushort4 c = hb4[s2 * 16 + q];
    ushort4 d = hb4[s3 * 16 + q];
    ax += bf2f(a.x) + bf2f(b.x) + bf2f(c.x) + bf2f(d.x);
    ay += bf2f(a.y) + bf2f(b.y) + bf2f(c.y) + bf2f(d.y);
    az += bf2f(a.z) + bf2f(b.z) + bf2f(c.z) + bf2f(d.z);
    aw += bf2f(a.w) + bf2f(b.w) + bf2f(c.w) + bf2f(d.w);
  }
  for (; k < p1; ++k) {
    ushort4 a = hb4[csr[k] * 16 + q];
    ax += bf2f(a.x); ay += bf2f(a.y); az += bf2f(a.z); aw += bf2f(a.w);
  }
  float inv = 1.0f / fmaxf((float)(p1 - p0), 1.0f);
  float4 o; o.x = ax * inv; o.y = ay * inv; o.z = az * inv; o.w = aw * inv;
  ((float4*)mean)[t] = o;
}

// ---------------------------------------------------------------------------
// Layer 1 tiled GEMM; epilogue writes h1 (f32) AND h1b (bf16).
// ---------------------------------------------------------------------------
__global__ __launch_bounds__(256) void layer1_gemm_kernel(
    const float* __restrict__ x, const float* __restrict__ mean,
    const float* __restrict__ Wl, const float* __restrict__ bl,
    const float* __restrict__ Wr, float* __restrict__ h1,
    unsigned short* __restrict__ h1b) {
  const int LD = 17;  // float4 row stride (16 data + 1 pad)
  __shared__ float4 sA[64 * LD];
  __shared__ float4 sB[64 * LD];
  __shared__ float sbias[64];
  int tid = threadIdx.x;
  int base = blockIdx.x * 64;
  const float4* mean4 = (const float4*)mean;
  const float4* x4 = (const float4*)x;
  const float4* Wl4 = (const float4*)Wl;
  const float4* Wr4 = (const float4*)Wr;
  const float4 zero = make_float4(0.f, 0.f, 0.f, 0.f);
  for (int idx = tid; idx < 64 * 16; idx += 256) {
    int row = idx >> 4, col = idx & 15;
    int node = base + row;
    float4 v = zero;
    if (node < N_NODES)
      v = (col < 8) ? mean4[node * 8 + col] : x4[node * 8 + (col - 8)];
    sA[row * LD + col] = v;
    sB[row * LD + col] = (col < 8) ? Wl4[row * 8 + col] : Wr4[row * 8 + (col - 8)];
  }
  if (tid < 64) sbias[tid] = bl[tid];
  __syncthreads();

  int tn = tid & 15;
  int to = tid >> 4;
  float acc[4][4];
#pragma unroll
  for (int i = 0; i < 4; ++i)
#pragma unroll
    for (int j = 0; j < 4; ++j) acc[i][j] = 0.f;

#pragma unroll 4
  for (int k4 = 0; k4 < 16; ++k4) {
    float4 a[4], b[4];
#pragma unroll
    for (int i = 0; i < 4; ++i) a[i] = sA[(tn + i * 16) * LD + k4];
#pragma unroll
    for (int j = 0; j < 4; ++j) b[j] = sB[(to * 4 + j) * LD + k4];
#pragma unroll
    for (int i = 0; i < 4; ++i)
#pragma unroll
      for (int j = 0; j < 4; ++j) {
        acc[i][j] = fmaf(a[i].x, b[j].x, acc[i][j]);
        acc[i][j] = fmaf(a[i].y, b[j].y, acc[i][j]);
        acc[i][j] = fmaf(a[i].z, b[j].z, acc[i][j]);
        acc[i][j] = fmaf(a[i].w, b[j].w, acc[i][j]);
      }
  }

  float4* h14 = (float4*)h1;
  ushort4* h1b4 = (ushort4*)h1b;
#pragma unroll
  for (int i = 0; i < 4; ++i) {
    int node = base + tn + i * 16;
    if (node < N_NODES) {
      float4 v;
      v.x = fmaxf(acc[i][0] + sbias[to * 4 + 0], 0.f);
      v.y = fmaxf(acc[i][1] + sbias[to * 4 + 1], 0.f);
      v.z = fmaxf(acc[i][2] + sbias[to * 4 + 2], 0.f);
      v.w = fmaxf(acc[i][3] + sbias[to * 4 + 3], 0.f);
      h14[node * 16 + to] = v;
      ushort4 hb;
      hb.x = f2bf(v.x); hb.y = f2bf(v.y); hb.z = f2bf(v.z); hb.w = f2bf(v.w);
      h1b4[node * 16 + to] = hb;
    }
  }
}

// ---------------------------------------------------------------------------
// Layer 2 + head fused.
// ---------------------------------------------------------------------------
__global__ __launch_bounds__(256) void layer2_head_kernel(
    const float* __restrict__ h1, const float* __restrict__ mean,
    const float* __restrict__ Wl, const float* __restrict__ bl,
    const float* __restrict__ Wr,
    const float* __restrict__ Wlin, const float* __restrict__ blin,
    float* __restrict__ out) {
  const int LD = 33;  // float4 row stride (32 data + 1 pad)
  __shared__ float4 sA[64 * LD];
  __shared__ float4 sB[64 * LD];
  __shared__ float sbias[64];
  __shared__ float sWlin[OUT_C * 64];
  __shared__ float sblin[OUT_C];
  int tid = threadIdx.x;
  int base = blockIdx.x * 64;
  const float4* mean4 = (const float4*)mean;
  const float4* h14 = (const float4*)h1;
  const float4* Wl4 = (const float4*)Wl;
  const float4* Wr4 = (const float4*)Wr;
  const float4 zero = make_float4(0.f, 0.f, 0.f, 0.f);
  for (int idx = tid; idx < 64 * 32; idx += 256) {
    int row = idx >> 5, col = idx & 31;
    int node = base + row;
    float4 v = zero;
    if (node < N_NODES)
      v = (col < 16) ? mean4[node * 16 + col] : h14[node * 16 + (col - 16)];
    sA[row * LD + col] = v;
    sB[row * LD + col] = (col < 16) ? Wl4[row * 16 + col] : Wr4[row * 16 + (col - 16)];
  }
  if (tid < 64) sbias[tid] = bl[tid];
  for (int i = tid; i < OUT_C * 64; i += 256) sWlin[i] = Wlin[i];
  if (tid < OUT_C) sblin[tid] = blin[tid];
  __syncthreads();

  int tn = tid & 15;
  int to = tid >> 4;
  float acc[4][4];
#pragma unroll
  for (int i = 0; i < 4; ++i)
#pragma unroll
    for (int j = 0; j < 4; ++j) acc[i][j] = 0.f;

#pragma unroll 4
  for (int k4 = 0; k4 < 32; ++k4) {
    float4 a[4], b[4];
#pragma unroll
    for (int i = 0; i < 4; ++i) a[i] = sA[(tn + i * 16) * LD + k4];
#pragma unroll
    for (int j = 0; j < 4; ++j) b[j] = sB[(to * 4 + j) * LD + k4];
#pragma unroll
    for (int i = 0; i < 4; ++i)
#pragma unroll
      for (int j = 0; j < 4; ++j) {
        acc[i][j] = fmaf(a[i].x, b[j].x, acc[i][j]);
        acc[i][j] = fmaf(a[i].y, b[j].y, acc[i][j]);
        acc[i][j] = fmaf(a[i].z, b[j].z, acc[i][j]);
        acc[i][j] = fmaf(a[i].w, b[j].w, acc[i][j]);
      }
  }

  __syncthreads();
  float* sH = (float*)sA;
  const int LDH = 69;
#pragma unroll
  for (int i = 0; i < 4; ++i) {
    int r = tn + i * 16;
#pragma unroll
    for (int j = 0; j < 4; ++j) {
      sH[r * LDH + to * 4 + j] = fmaxf(acc[i][j] + sbias[to * 4 + j], 0.f);
    }
  }
  __syncthreads();

  if (tid < 64) {
    int node = base + tid;
    if (node < N_NODES) {
      float o5[OUT_C];
#pragma unroll
      for (int m = 0; m < OUT_C; ++m) o5[m] = sblin[m];
      const float* hr = &sH[tid * LDH];
#pragma unroll 8
      for (int c = 0; c < HID_C; ++c) {
        float v = hr[c];
#pragma unroll
        for (int m = 0; m < OUT_C; ++m) o5[m] = fmaf(v, sWlin[m * 64 + c], o5[m]);
      }
#pragma unroll
      for (int m = 0; m < OUT_C; ++m) out[node * OUT_C + m] = o5[m];
    }
  }
}

extern "C" void kernel_launch(void* const* d_in, const int* in_sizes, int n_in,
                              void* d_out, int out_size, void* d_ws, size_t ws_size,
                              hipStream_t stream) {
  const float* x    = (const float*)d_in[0];
  const int*   ei   = (const int*)d_in[1];
  const float* W1l  = (const float*)d_in[2];
  const float* b1   = (const float*)d_in[3];
  const float* W1r  = (const float*)d_in[4];
  const float* W2l  = (const float*)d_in[5];
  const float* b2   = (const float*)d_in[6];
  const float* W2r  = (const float*)d_in[7];
  const float* Wlin = (const float*)d_in[8];
  const float* blin = (const float*)d_in[9];

  const int* src = ei;
  const int* dst = ei + N_EDGES;

  // Workspace layout (4B units):
  //   rowptr  [100004]
  //   cnt     [100000]   (histogram)
  //   partial [128]
  //   rank    [1600000]  (per-edge rank within dst row)
  //   csr_src [1600000]
  //   xb      [N*32/2]   (bf16 x)
  //   h1b     [N*64/2]   (bf16 h1)
  //   mean    [N*64]
  //   h1      [N*64]
  int* rowptr  = (int*)d_ws;
  int* cnt     = rowptr + 100004;
  int* partial = cnt + N_NODES;
  int* rank    = partial + 128;
  int* csr_src = rank + N_EDGES;
  unsigned short* xb  = (unsigned short*)(csr_src + N_EDGES);
  unsigned short* h1b = xb + (size_t)N_NODES * IN_C;
  float* mean  = (float*)(h1b + (size_t)N_NODES * HID_C);
  float* h1    = mean + (size_t)N_NODES * HID_C;

  hipMemsetAsync(cnt, 0, (size_t)N_NODES * sizeof(int), stream);

  convert_x_kernel<<<(N_NODES * IN_C / 4 + 255) / 256, 256, 0, stream>>>(x, xb);
  deg_count_kernel<<<PART_BLOCKS, 256, 0, stream>>>(dst, cnt, rank);
  scan1_kernel<<<N_SCAN_BLKS, SCAN_BLK, 0, stream>>>(cnt, rowptr, partial);
  scan2_kernel<<<1, 128, 0, stream>>>(partial);
  scan3_kernel<<<(N_NODES + 255) / 256, 256, 0, stream>>>(rowptr, partial);
  fill_kernel<<<PART_BLOCKS, 256, 0, stream>>>(src, dst, rank, rowptr, csr_src);

  agg_mean1_kernel<<<(N_NODES * (IN_C / 4) + 255) / 256, 256, 0, stream>>>(
      xb, rowptr, csr_src, mean);
  layer1_gemm_kernel<<<N_TILES, 256, 0, stream>>>(
      x, mean, W1l, b1, W1r, h1, h1b);
  agg_mean2_kernel<<<(N_NODES * (HID_C / 4) + 255) / 256, 256, 0, stream>>>(
      h1b, rowptr, csr_src, mean);
  layer2_head_kernel<<<N_TILES, 256, 0, stream>>>(
      h1, mean, W2l, b2, W2r, Wlin, blin, (float*)d_out);
}

// Round 17
// 258.946 us; speedup vs baseline: 2.2802x; 1.0162x over previous
//
#include <hip/hip_runtime.h>

#define N_NODES 100000
#define IN_C 32
#define HID_C 64
#define OUT_C 5
#define N_EDGES 1600000
#define SCAN_BLK 1024
#define N_SCAN_BLKS ((N_NODES + SCAN_BLK - 1) / SCAN_BLK)   // 98
#define N_TILES ((N_NODES + 63) / 64)                        // 1563

// dst-space partitioning for XCD-local scatter writes — used ONLY in fill,
// where the scattered csr_src stores need line locality (R9->R12 proven).
#define N_PART 8
#define PART_NODES 12500
#define PART_BLOCKS 2048

__device__ __forceinline__ unsigned short f2bf(float f) {
  unsigned int u = __float_as_uint(f);
  unsigned int r = (u + 0x7FFFu + ((u >> 16) & 1u)) >> 16;  // RNE
  return (unsigned short)r;
}
__device__ __forceinline__ float bf2f(unsigned short b) {
  return __uint_as_float(((unsigned int)b) << 16);
}

// ---------------------------------------------------------------------------
// Convert x (f32 [N,32]) -> xb (bf16).
// ---------------------------------------------------------------------------
__global__ __launch_bounds__(256) void convert_x_kernel(
    const float* __restrict__ x, unsigned short* __restrict__ xb) {
  int t = blockIdx.x * blockDim.x + threadIdx.x;
  if (t >= N_NODES * IN_C / 4) return;
  float4 v = ((const float4*)x)[t];
  ushort4 o;
  o.x = f2bf(v.x); o.y = f2bf(v.y); o.z = f2bf(v.z); o.w = f2bf(v.w);
  ((ushort4*)xb)[t] = o;
}

// ---------------------------------------------------------------------------
// CSR build step 1: UNPARTITIONED histogram + rank. One coalesced pass;
// rank writes are dense (6.4 MB). Device-scope atomics on cnt (400 KB)
// are cheap (~300 G atomics/s measured in R1).
// ---------------------------------------------------------------------------
__global__ __launch_bounds__(256) void deg_count_kernel(
    const int* __restrict__ dst, int* __restrict__ cnt,
    int* __restrict__ rank) {
  int e = blockIdx.x * blockDim.x + threadIdx.x;
  if (e >= N_EDGES) return;
  rank[e] = atomicAdd(&cnt[dst[e]], 1);
}

// ---------------------------------------------------------------------------
// CSR build step 2a: per-block inclusive scan of cnt.
// ---------------------------------------------------------------------------
__global__ __launch_bounds__(SCAN_BLK) void scan1_kernel(
    const int* __restrict__ cnt, int* __restrict__ rowptr,
    int* __restrict__ partial) {
  __shared__ int s[SCAN_BLK];
  int t = threadIdx.x;
  int g = blockIdx.x * SCAN_BLK + t;
  int v = (g < N_NODES) ? cnt[g] : 0;
  s[t] = v;
  __syncthreads();
#pragma unroll
  for (int off = 1; off < SCAN_BLK; off <<= 1) {
    int u = (t >= off) ? s[t - off] : 0;
    __syncthreads();
    s[t] += u;
    __syncthreads();
  }
  if (g < N_NODES) rowptr[g + 1] = s[t];
  if (t == SCAN_BLK - 1) partial[blockIdx.x] = s[t];
}

// ---------------------------------------------------------------------------
// CSR build step 2b: exclusive scan of block totals (single block).
// ---------------------------------------------------------------------------
__global__ __launch_bounds__(128) void scan2_kernel(int* __restrict__ partial) {
  __shared__ int s[128];
  int t = threadIdx.x;
  int v = (t < N_SCAN_BLKS) ? partial[t] : 0;
  s[t] = v;
  __syncthreads();
#pragma unroll
  for (int off = 1; off < 128; off <<= 1) {
    int u = (t >= off) ? s[t - off] : 0;
    __syncthreads();
    s[t] += u;
    __syncthreads();
  }
  if (t < N_SCAN_BLKS) partial[t] = s[t] - v;  // exclusive
}

// ---------------------------------------------------------------------------
// CSR build step 2c: add block offsets -> final rowptr.
// ---------------------------------------------------------------------------
__global__ __launch_bounds__(256) void scan3_kernel(
    int* __restrict__ rowptr, const int* __restrict__ partial) {
  int i = blockIdx.x * blockDim.x + threadIdx.x;
  if (i >= N_NODES) return;
  rowptr[i + 1] += partial[i >> 10];
  if (i == 0) rowptr[0] = 0;
}

// ---------------------------------------------------------------------------
// CSR build step 3: fill csr_src — NO atomics. Placement is
// rowptr[dst] + rank[e]. XCD-partitioned for csr_src write locality.
// ---------------------------------------------------------------------------
__global__ __launch_bounds__(256) void fill_kernel(
    const int* __restrict__ src, const int* __restrict__ dst,
    const int* __restrict__ rank, const int* __restrict__ rowptr,
    int* __restrict__ csr_src) {
  int r = blockIdx.x & (N_PART - 1);
  int tid = (blockIdx.x >> 3) * 256 + threadIdx.x;
  const int stride = (PART_BLOCKS >> 3) * 256;
  int lo = r * PART_NODES, hi = lo + PART_NODES;
  for (int e = tid; e < N_EDGES; e += stride) {
    int d = dst[e];
    if (d >= lo && d < hi) {
      csr_src[rowptr[d] + rank[e]] = src[e];
    }
  }
}

// ---------------------------------------------------------------------------
// Mean aggregation layer 1 (gather of bf16 x rows, f32 accumulate).
// ---------------------------------------------------------------------------
__global__ __launch_bounds__(256) void agg_mean1_kernel(
    const unsigned short* __restrict__ xb, const int* __restrict__ rowptr,
    const int* __restrict__ csr, float* __restrict__ mean) {
  int t = blockIdx.x * blockDim.x + threadIdx.x;
  if (t >= N_NODES * (IN_C / 4)) return;
  int node = t >> 3;
  int q = t & 7;
  int p0 = rowptr[node], p1 = rowptr[node + 1];
  const ushort4* xb4 = (const ushort4*)xb;
  float ax = 0.f, ay = 0.f, az = 0.f, aw = 0.f;
  int k = p0;
  for (; k + 4 <= p1; k += 4) {
    int s0 = csr[k], s1 = csr[k + 1], s2 = csr[k + 2], s3 = csr[k + 3];
    ushort4 a = xb4[s0 * 8 + q];
    ushort4 b = xb4[s1 * 8 + q];
    ushort4 c = xb4[s2 * 8 + q];
    ushort4 d = xb4[s3 * 8 + q];
    ax += bf2f(a.x) + bf2f(b.x) + bf2f(c.x) + bf2f(d.x);
    ay += bf2f(a.y) + bf2f(b.y) + bf2f(c.y) + bf2f(d.y);
    az += bf2f(a.z) + bf2f(b.z) + bf2f(c.z) + bf2f(d.z);
    aw += bf2f(a.w) + bf2f(b.w) + bf2f(c.w) + bf2f(d.w);
  }
  for (; k < p1; ++k) {
    ushort4 a = xb4[csr[k] * 8 + q];
    ax += bf2f(a.x); ay += bf2f(a.y); az += bf2f(a.z); aw += bf2f(a.w);
  }
  float inv = 1.0f / fmaxf((float)(p1 - p0), 1.0f);
  float4 o; o.x = ax * inv; o.y = ay * inv; o.z = az * inv; o.w = aw * inv;
  ((float4*)mean)[t] = o;
}

// ---------------------------------------------------------------------------
// Mean aggregation layer 2 (gather of bf16 h1 rows, f32 accumulate).
// ---------------------------------------------------------------------------
__global__ __launch_bounds__(256) void agg_mean2_kernel(
    const unsigned short* __restrict__ hb, const int* __restrict__ rowptr,
    const int* __restrict__ csr, float* __restrict__ mean) {
  int t = blockIdx.x * blockDim.x + threadIdx.x;
  if (t >= N_NODES * (HID_C / 4)) return;
  int node = t >> 4;
  int q = t & 15;
  int p0 = rowptr[node], p1 = rowptr[node + 1];
  const ushort4* hb4 = (const ushort4*)hb;
  float ax = 0.f, ay = 0.f, az = 0.f, aw = 0.f;
  int k = p0;
  for (; k + 4 <= p1; k += 4) {
    int s0 = csr[k], s1 = csr[k + 1], s2 = csr[k + 2], s3 = csr[k + 3];
    ushort4 a = hb4[s0 * 16 + q];
    ushort4 b = hb4[s1 * 16 + q];
    ushort4 c = hb4[s2 * 16 + q];
    ushort4 d = hb4[s3 * 16 + q];
    ax += bf2f(a.x) + bf2f(b.x) + bf2f(c.x) + bf2f(d.x);
    ay += bf2f(a.y) + bf2f(b.y) + bf2f(c.y) + bf2f(d.y);
    az += bf2f(a.z) + bf2f(b.z) + bf2f(c.z) + bf2f(d.z);
    aw += bf2f(a.w) + bf2f(b.w) + bf2f(c.w) + bf2f(d.w);
  }
  for (; k < p1; ++k) {
    ushort4 a = hb4[csr[k] * 16 + q];
    ax += bf2f(a.x); ay += bf2f(a.y); az += bf2f(a.z); aw += bf2f(a.w);
  }
  float inv = 1.0f / fmaxf((float)(p1 - p0), 1.0f);
  float4 o; o.x = ax * inv; o.y = ay * inv; o.z = az * inv; o.w = aw * inv;
  ((float4*)mean)[t] = o;
}

// ---------------------------------------------------------------------------
// Layer 1 tiled GEMM; epilogue writes h1 (f32) AND h1b (bf16).
// ---------------------------------------------------------------------------
__global__ __launch_bounds__(256) void layer1_gemm_kernel(
    const float* __restrict__ x, const float* __restrict__ mean,
    const float* __restrict__ Wl, const float* __restrict__ bl,
    const float* __restrict__ Wr, float* __restrict__ h1,
    unsigned short* __restrict__ h1b) {
  const int LD = 17;  // float4 row stride (16 data + 1 pad)
  __shared__ float4 sA[64 * LD];
  __shared__ float4 sB[64 * LD];
  __shared__ float sbias[64];
  int tid = threadIdx.x;
  int base = blockIdx.x * 64;
  const float4* mean4 = (const float4*)mean;
  const float4* x4 = (const float4*)x;
  const float4* Wl4 = (const float4*)Wl;
  const float4* Wr4 = (const float4*)Wr;
  const float4 zero = make_float4(0.f, 0.f, 0.f, 0.f);
  for (int idx = tid; idx < 64 * 16; idx += 256) {
    int row = idx >> 4, col = idx & 15;
    int node = base + row;
    float4 v = zero;
    if (node < N_NODES)
      v = (col < 8) ? mean4[node * 8 + col] : x4[node * 8 + (col - 8)];
    sA[row * LD + col] = v;
    sB[row * LD + col] = (col < 8) ? Wl4[row * 8 + col] : Wr4[row * 8 + (col - 8)];
  }
  if (tid < 64) sbias[tid] = bl[tid];
  __syncthreads();

  int tn = tid & 15;
  int to = tid >> 4;
  float acc[4][4];
#pragma unroll
  for (int i = 0; i < 4; ++i)
#pragma unroll
    for (int j = 0; j < 4; ++j) acc[i][j] = 0.f;

#pragma unroll 4
  for (int k4 = 0; k4 < 16; ++k4) {
    float4 a[4], b[4];
#pragma unroll
    for (int i = 0; i < 4; ++i) a[i] = sA[(tn + i * 16) * LD + k4];
#pragma unroll
    for (int j = 0; j < 4; ++j) b[j] = sB[(to * 4 + j) * LD + k4];
#pragma unroll
    for (int i = 0; i < 4; ++i)
#pragma unroll
      for (int j = 0; j < 4; ++j) {
        acc[i][j] = fmaf(a[i].x, b[j].x, acc[i][j]);
        acc[i][j] = fmaf(a[i].y, b[j].y, acc[i][j]);
        acc[i][j] = fmaf(a[i].z, b[j].z, acc[i][j]);
        acc[i][j] = fmaf(a[i].w, b[j].w, acc[i][j]);
      }
  }

  float4* h14 = (float4*)h1;
  ushort4* h1b4 = (ushort4*)h1b;
#pragma unroll
  for (int i = 0; i < 4; ++i) {
    int node = base + tn + i * 16;
    if (node < N_NODES) {
      float4 v;
      v.x = fmaxf(acc[i][0] + sbias[to * 4 + 0], 0.f);
      v.y = fmaxf(acc[i][1] + sbias[to * 4 + 1], 0.f);
      v.z = fmaxf(acc[i][2] + sbias[to * 4 + 2], 0.f);
      v.w = fmaxf(acc[i][3] + sbias[to * 4 + 3], 0.f);
      h14[node * 16 + to] = v;
      ushort4 hb;
      hb.x = f2bf(v.x); hb.y = f2bf(v.y); hb.z = f2bf(v.z); hb.w = f2bf(v.w);
      h1b4[node * 16 + to] = hb;
    }
  }
}

// ---------------------------------------------------------------------------
// Layer 2 + head fused.
// ---------------------------------------------------------------------------
__global__ __launch_bounds__(256) void layer2_head_kernel(
    const float* __restrict__ h1, const float* __restrict__ mean,
    const float* __restrict__ Wl, const float* __restrict__ bl,
    const float* __restrict__ Wr,
    const float* __restrict__ Wlin, const float* __restrict__ blin,
    float* __restrict__ out) {
  const int LD = 33;  // float4 row stride (32 data + 1 pad)
  __shared__ float4 sA[64 * LD];
  __shared__ float4 sB[64 * LD];
  __shared__ float sbias[64];
  __shared__ float sWlin[OUT_C * 64];
  __shared__ float sblin[OUT_C];
  int tid = threadIdx.x;
  int base = blockIdx.x * 64;
  const float4* mean4 = (const float4*)mean;
  const float4* h14 = (const float4*)h1;
  const float4* Wl4 = (const float4*)Wl;
  const float4* Wr4 = (const float4*)Wr;
  const float4 zero = make_float4(0.f, 0.f, 0.f, 0.f);
  for (int idx = tid; idx < 64 * 32; idx += 256) {
    int row = idx >> 5, col = idx & 31;
    int node = base + row;
    float4 v = zero;
    if (node < N_NODES)
      v = (col < 16) ? mean4[node * 16 + col] : h14[node * 16 + (col - 16)];
    sA[row * LD + col] = v;
    sB[row * LD + col] = (col < 16) ? Wl4[row * 16 + col] : Wr4[row * 16 + (col - 16)];
  }
  if (tid < 64) sbias[tid] = bl[tid];
  for (int i = tid; i < OUT_C * 64; i += 256) sWlin[i] = Wlin[i];
  if (tid < OUT_C) sblin[tid] = blin[tid];
  __syncthreads();

  int tn = tid & 15;
  int to = tid >> 4;
  float acc[4][4];
#pragma unroll
  for (int i = 0; i < 4; ++i)
#pragma unroll
    for (int j = 0; j < 4; ++j) acc[i][j] = 0.f;

#pragma unroll 4
  for (int k4 = 0; k4 < 32; ++k4) {
    float4 a[4], b[4];
#pragma unroll
    for (int i = 0; i < 4; ++i) a[i] = sA[(tn + i * 16) * LD + k4];
#pragma unroll
    for (int j = 0; j < 4; ++j) b[j] = sB[(to * 4 + j) * LD + k4];
#pragma unroll
    for (int i = 0; i < 4; ++i)
#pragma unroll
      for (int j = 0; j < 4; ++j) {
        acc[i][j] = fmaf(a[i].x, b[j].x, acc[i][j]);
        acc[i][j] = fmaf(a[i].y, b[j].y, acc[i][j]);
        acc[i][j] = fmaf(a[i].z, b[j].z, acc[i][j]);
        acc[i][j] = fmaf(a[i].w, b[j].w, acc[i][j]);
      }
  }

  __syncthreads();
  float* sH = (float*)sA;
  const int LDH = 69;
#pragma unroll
  for (int i = 0; i < 4; ++i) {
    int r = tn + i * 16;
#pragma unroll
    for (int j = 0; j < 4; ++j) {
      sH[r * LDH + to * 4 + j] = fmaxf(acc[i][j] + sbias[to * 4 + j], 0.f);
    }
  }
  __syncthreads();

  if (tid < 64) {
    int node = base + tid;
    if (node < N_NODES) {
      float o5[OUT_C];
#pragma unroll
      for (int m = 0; m < OUT_C; ++m) o5[m] = sblin[m];
      const float* hr = &sH[tid * LDH];
#pragma unroll 8
      for (int c = 0; c < HID_C; ++c) {
        float v = hr[c];
#pragma unroll
        for (int m = 0; m < OUT_C; ++m) o5[m] = fmaf(v, sWlin[m * 64 + c], o5[m]);
      }
#pragma unroll
      for (int m = 0; m < OUT_C; ++m) out[node * OUT_C + m] = o5[m];
    }
  }
}

extern "C" void kernel_launch(void* const* d_in, const int* in_sizes, int n_in,
                              void* d_out, int out_size, void* d_ws, size_t ws_size,
                              hipStream_t stream) {
  const float* x    = (const float*)d_in[0];
  const int*   ei   = (const int*)d_in[1];
  const float* W1l  = (const float*)d_in[2];
  const float* b1   = (const float*)d_in[3];
  const float* W1r  = (const float*)d_in[4];
  const float* W2l  = (const float*)d_in[5];
  const float* b2   = (const float*)d_in[6];
  const float* W2r  = (const float*)d_in[7];
  const float* Wlin = (const float*)d_in[8];
  const float* blin = (const float*)d_in[9];

  const int* src = ei;
  const int* dst = ei + N_EDGES;

  // Workspace layout (4B units):
  //   rowptr  [100004]
  //   cnt     [100000]   (histogram)
  //   partial [128]
  //   rank    [1600000]  (per-edge rank within dst row)
  //   csr_src [1600000]
  //   xb      [N*32/2]   (bf16 x)
  //   h1b     [N*64/2]   (bf16 h1)
  //   mean    [N*64]
  //   h1      [N*64]
  int* rowptr  = (int*)d_ws;
  int* cnt     = rowptr + 100004;
  int* partial = cnt + N_NODES;
  int* rank    = partial + 128;
  int* csr_src = rank + N_EDGES;
  unsigned short* xb  = (unsigned short*)(csr_src + N_EDGES);
  unsigned short* h1b = xb + (size_t)N_NODES * IN_C;
  float* mean  = (float*)(h1b + (size_t)N_NODES * HID_C);
  float* h1    = mean + (size_t)N_NODES * HID_C;

  hipMemsetAsync(cnt, 0, (size_t)N_NODES * sizeof(int), stream);

  convert_x_kernel<<<(N_NODES * IN_C / 4 + 255) / 256, 256, 0, stream>>>(x, xb);
  deg_count_kernel<<<(N_EDGES + 255) / 256, 256, 0, stream>>>(dst, cnt, rank);
  scan1_kernel<<<N_SCAN_BLKS, SCAN_BLK, 0, stream>>>(cnt, rowptr, partial);
  scan2_kernel<<<1, 128, 0, stream>>>(partial);
  scan3_kernel<<<(N_NODES + 255) / 256, 256, 0, stream>>>(rowptr, partial);
  fill_kernel<<<PART_BLOCKS, 256, 0, stream>>>(src, dst, rank, rowptr, csr_src);

  agg_mean1_kernel<<<(N_NODES * (IN_C / 4) + 255) / 256, 256, 0, stream>>>(
      xb, rowptr, csr_src, mean);
  layer1_gemm_kernel<<<N_TILES, 256, 0, stream>>>(
      x, mean, W1l, b1, W1r, h1, h1b);
  agg_mean2_kernel<<<(N_NODES * (HID_C / 4) + 255) / 256, 256, 0, stream>>>(
      h1b, rowptr, csr_src, mean);
  layer2_head_kernel<<<N_TILES, 256, 0, stream>>>(
      h1, mean, W2l, b2, W2r, Wlin, blin, (float*)d_out);
}